// Round 9
// baseline (9375.767 us; speedup 1.0000x reference)
//
#include <hip/hip_runtime.h>
#include <stdint.h>

#define B_  256
#define T_  512
#define IN_ 64
#define H_  512
#define G4_ 2048
#define NC_ 64
#define H2_ 256

typedef _Float16 f16;
typedef __attribute__((ext_vector_type(4))) _Float16 f16x4;
typedef __attribute__((ext_vector_type(4))) float    f32x4;
typedef __attribute__((ext_vector_type(4))) unsigned int u32x4;

__device__ __forceinline__ float sigf(float x) {
  return __builtin_amdgcn_rcpf(1.0f + __expf(-x));
}
__device__ __forceinline__ float tanh_fast(float x) {
  x = fminf(fmaxf(x, -15.f), 15.f);
  const float e = __expf(2.f * x);
  return (e - 1.f) * __builtin_amdgcn_rcpf(e + 1.f);
}

// L3-coherent (cache-bypassing) helpers; wait_vm0 before consuming results.
__device__ __forceinline__ void store_u32_l3(void* p, unsigned v) {
  asm volatile("global_store_dword %0, %1, off sc0 sc1" :: "v"(p), "v"(v) : "memory");
}
__device__ __forceinline__ unsigned load_u32_l3(const void* p) {
  unsigned r;
  asm volatile("global_load_dword %0, %1, off sc0 sc1" : "=v"(r) : "v"(p) : "memory");
  return r;
}
__device__ __forceinline__ u32x4 load_u32x4_l3(const void* p) {
  u32x4 r;
  asm volatile("global_load_dwordx4 %0, %1, off sc0 sc1" : "=v"(r) : "v"(p) : "memory");
  return r;
}
__device__ __forceinline__ void wait_vm0() {
  asm volatile("s_waitcnt vmcnt(0)" ::: "memory");
}

// ---------------- prep kernels ----------------
__global__ void cvt_f32_f16(const float* __restrict__ s, f16* __restrict__ d, int n) {
  int i = blockIdx.x * blockDim.x + threadIdx.x;
  int st = gridDim.x * blockDim.x;
  for (; i < n; i += st) d[i] = (f16)s[i];
}

__global__ void bias_comb(const float* __restrict__ a, const float* __restrict__ b,
                          float* __restrict__ d, int n) {
  int i = blockIdx.x * blockDim.x + threadIdx.x;
  if (i < n) d[i] = a[i] + b[i];
}

// ---------------- fused pipelined 2-layer LSTM ----------------
// 256 WGs x 512 threads, 1 WG/CU. Weight streams are the pacer -> per-WG
// stream halved (M=32, NS=16) and weight slices made XCD-local via bid&7.
// role A (bid 0..127):   layer-0 scan; streams wih0+whh0 slice (144 KB/step).
// role C (bid 128..255): layer-1 scan; streams wih1+whh1 slice (256 KB/step);
//                        gx1 computed inline (no intermediate buffer).
// WG (grp, sl): batch rows grp*32..+31, h-cols sl*32..+31 (128 gate rows).
// sl = (bid&7)*2 + ((bid>>3)&1)  -> XCD x hosts only slices {2x, 2x+1}.
// flags slot i at flags[i*16]: [0,128)=A (grp*16+sl), [128,256)=C. value=steps done.
__global__ __launch_bounds__(512, 2) void fused_g(
    const f16* __restrict__ x16,     // [B][T][64]
    const f16* __restrict__ wih0,    // [2048][64]
    const f16* __restrict__ whh0,    // [2048][512]
    const f16* __restrict__ wih1,    // [2048][512]
    const f16* __restrict__ whh1,    // [2048][512]
    const float* __restrict__ bias0, // [2048]
    const float* __restrict__ bias1, // [2048]
    f16* __restrict__ h0seq,         // [T][B][512]
    f16* __restrict__ hbuf1,         // [2][B][512]
    unsigned* __restrict__ flags) {
  __shared__ __align__(16) unsigned char smem[85504];
  const int bid = blockIdx.x;
  const int tid = threadIdx.x;
  const int lane = tid & 63, wv = tid >> 6;        // 8 waves
  const int l15 = lane & 15, hi = lane >> 4;

  const int rb = (bid < 128) ? bid : (bid - 128);
  const int k8 = rb >> 3;                          // 0..15
  const int sl = ((rb & 7) << 1) | (k8 & 1);       // 0..15, XCD-local pairs
  const int grp = k8 >> 1;                         // 0..7

  // shared per-role geometry
  const int lg = wv * 16 + l15;                    // local gate row 0..127
  const int grow = (lg >> 5) * H_ + sl * 32 + (lg & 31);
  const int row = tid >> 4;                        // owned state row 0..31
  const int j0 = (tid & 15) * 2;                   // owned h-col pair
  const int hrow = tid >> 4, hcol = (tid & 15) * 32;  // staging: 32 rows x 16 thr

  if (bid < 128) {
    // ================= role A: layer-0 scan =================
    f16 (*xt)[72]    = (f16(*)[72])smem;                         // 4608 B
    f16 (*ht)[536]   = (f16(*)[536])(smem + 4608);               // 34304 B
    float (*gl)[132] = (float(*)[132])(smem + 4608 + 34304);     // 16896 B

    const float bv = bias0[grow];
    const f16* wihp = wih0 + (size_t)grow * IN_ + 4 * hi;
    const f16* whhp = whh0 + (size_t)grow * H_ + 4 * hi;

    float c0 = 0.f, c1 = 0.f;

    for (int t = 0; t < T_; ++t) {
      // x(t) tile (independent of recurrence)
      if (tid < 256) {
        const f16* xs = x16 + ((size_t)(grp * 32 + (tid >> 3)) * T_ + t) * IN_ + (tid & 7) * 8;
        *(uint4*)&xt[tid >> 3][(tid & 7) * 8] = *(const uint4*)xs;
      }
      if (t != 0) {
        const unsigned* pp = flags + (size_t)(grp * 16 + (lane & 15)) * 16;
        const unsigned want = (unsigned)t;
        for (;;) {
          unsigned v = load_u32_l3(pp); wait_vm0();
          if (__all((int)(v >= want))) break;
          __builtin_amdgcn_s_sleep(1);
        }
        const f16* hs = h0seq + ((size_t)(t - 1) * B_ + grp * 32 + hrow) * H_ + hcol;
        u32x4 r0 = load_u32x4_l3(hs);
        u32x4 r1 = load_u32x4_l3(hs + 8);
        u32x4 r2 = load_u32x4_l3(hs + 16);
        u32x4 r3 = load_u32x4_l3(hs + 24);
        wait_vm0();
        __builtin_amdgcn_sched_barrier(0);
        *(u32x4*)&ht[hrow][hcol]      = r0;
        *(u32x4*)&ht[hrow][hcol + 8]  = r1;
        *(u32x4*)&ht[hrow][hcol + 16] = r2;
        *(u32x4*)&ht[hrow][hcol + 24] = r3;
      } else {
        u32x4 z = {0u, 0u, 0u, 0u};
        *(u32x4*)&ht[hrow][hcol]      = z;
        *(u32x4*)&ht[hrow][hcol + 8]  = z;
        *(u32x4*)&ht[hrow][hcol + 16] = z;
        *(u32x4*)&ht[hrow][hcol + 24] = z;
      }
      __syncthreads();

      f32x4 acc[2];
      acc[0][0] = bv; acc[0][1] = bv; acc[0][2] = bv; acc[0][3] = bv;
      acc[1] = acc[0];
#pragma unroll
      for (int ks = 0; ks < 4; ++ks) {
        const f16x4 a0 = *(const f16x4*)&xt[l15][ks * 16 + 4 * hi];
        const f16x4 a1 = *(const f16x4*)&xt[16 + l15][ks * 16 + 4 * hi];
        const f16x4 w  = *(const f16x4*)(wihp + ks * 16);
        acc[0] = __builtin_amdgcn_mfma_f32_16x16x16f16(a0, w, acc[0], 0, 0, 0);
        acc[1] = __builtin_amdgcn_mfma_f32_16x16x16f16(a1, w, acc[1], 0, 0, 0);
      }
#pragma unroll
      for (int ks = 0; ks < 32; ++ks) {
        const f16x4 a0 = *(const f16x4*)&ht[l15][ks * 16 + 4 * hi];
        const f16x4 a1 = *(const f16x4*)&ht[16 + l15][ks * 16 + 4 * hi];
        const f16x4 w  = *(const f16x4*)(whhp + ks * 16);      // L2-hot stream
        acc[0] = __builtin_amdgcn_mfma_f32_16x16x16f16(a0, w, acc[0], 0, 0, 0);
        acc[1] = __builtin_amdgcn_mfma_f32_16x16x16f16(a1, w, acc[1], 0, 0, 0);
      }
      const int col = wv * 16 + l15;
#pragma unroll
      for (int mt = 0; mt < 2; ++mt)
#pragma unroll
        for (int r = 0; r < 4; ++r) gl[mt * 16 + 4 * hi + r][col] = acc[mt][r];
      __syncthreads();

      const float gi = gl[row][j0],       gi1 = gl[row][j0 + 1];
      const float gf = gl[row][32 + j0],  gf1 = gl[row][32 + j0 + 1];
      const float gg = gl[row][64 + j0],  gg1 = gl[row][64 + j0 + 1];
      const float go = gl[row][96 + j0],  go1 = gl[row][96 + j0 + 1];
      c0 = sigf(gf) * c0 + sigf(gi) * tanh_fast(gg);
      c1 = sigf(gf1) * c1 + sigf(gi1) * tanh_fast(gg1);
      const f16 ha = (f16)(sigf(go) * tanh_fast(c0));
      const f16 hb = (f16)(sigf(go1) * tanh_fast(c1));
      unsigned hp = ((unsigned)__builtin_bit_cast(unsigned short, hb) << 16)
                  |  (unsigned)__builtin_bit_cast(unsigned short, ha);
      store_u32_l3(h0seq + ((size_t)t * B_ + grp * 32 + row) * H_ + sl * 32 + j0, hp);
      wait_vm0();
      __syncthreads();
      if (tid == 0) store_u32_l3(flags + (size_t)(grp * 16 + sl) * 16, (unsigned)(t + 1));
    }

  } else {
    // ================= role C: layer-1 scan, inline gx1 =================
    f16 (*ht0)[536]  = (f16(*)[536])smem;                        // h0(t)
    f16 (*ht1)[536]  = (f16(*)[536])(smem + 34304);              // h1(t-1)
    float (*gl)[132] = (float(*)[132])(smem + 68608);

    const float bv = bias1[grow];
    const f16* wihp = wih1 + (size_t)grow * H_ + 4 * hi;
    const f16* whhp = whh1 + (size_t)grow * H_ + 4 * hi;

    float c0 = 0.f, c1 = 0.f;

    for (int t = 0; t < T_; ++t) {
      // merged poll: lanes 0-15 -> A peers (want t+1); lanes 16-31 -> own C peers (want t)
      {
        const int la = lane & 31;
        const unsigned* pp;
        unsigned want;
        if (la < 16) { pp = flags + (size_t)(grp * 16 + la) * 16;        want = (unsigned)(t + 1); }
        else         { pp = flags + (size_t)(128 + grp * 16 + (la - 16)) * 16; want = (unsigned)t; }
        for (;;) {
          unsigned v = load_u32_l3(pp); wait_vm0();
          if (__all((int)(v >= want))) break;
          __builtin_amdgcn_s_sleep(1);
        }
      }
      // stage h0(t) and h1(t-1); one drain
      {
        const f16* hs0 = h0seq + ((size_t)t * B_ + grp * 32 + hrow) * H_ + hcol;
        u32x4 r0 = load_u32x4_l3(hs0);
        u32x4 r1 = load_u32x4_l3(hs0 + 8);
        u32x4 r2 = load_u32x4_l3(hs0 + 16);
        u32x4 r3 = load_u32x4_l3(hs0 + 24);
        if (t != 0) {
          const f16* hs1 = hbuf1 + ((size_t)((t - 1) & 1) * B_ + grp * 32 + hrow) * H_ + hcol;
          u32x4 s0 = load_u32x4_l3(hs1);
          u32x4 s1 = load_u32x4_l3(hs1 + 8);
          u32x4 s2 = load_u32x4_l3(hs1 + 16);
          u32x4 s3 = load_u32x4_l3(hs1 + 24);
          wait_vm0();
          __builtin_amdgcn_sched_barrier(0);
          *(u32x4*)&ht1[hrow][hcol]      = s0;
          *(u32x4*)&ht1[hrow][hcol + 8]  = s1;
          *(u32x4*)&ht1[hrow][hcol + 16] = s2;
          *(u32x4*)&ht1[hrow][hcol + 24] = s3;
        } else {
          wait_vm0();
          __builtin_amdgcn_sched_barrier(0);
          u32x4 z = {0u, 0u, 0u, 0u};
          *(u32x4*)&ht1[hrow][hcol]      = z;
          *(u32x4*)&ht1[hrow][hcol + 8]  = z;
          *(u32x4*)&ht1[hrow][hcol + 16] = z;
          *(u32x4*)&ht1[hrow][hcol + 24] = z;
        }
        *(u32x4*)&ht0[hrow][hcol]      = r0;
        *(u32x4*)&ht0[hrow][hcol + 8]  = r1;
        *(u32x4*)&ht0[hrow][hcol + 16] = r2;
        *(u32x4*)&ht0[hrow][hcol + 24] = r3;
      }
      __syncthreads();

      f32x4 acc[2];
      acc[0][0] = bv; acc[0][1] = bv; acc[0][2] = bv; acc[0][3] = bv;
      acc[1] = acc[0];
#pragma unroll
      for (int ks = 0; ks < 32; ++ks) {
        const f16x4 a0 = *(const f16x4*)&ht0[l15][ks * 16 + 4 * hi];
        const f16x4 a1 = *(const f16x4*)&ht0[16 + l15][ks * 16 + 4 * hi];
        const f16x4 w  = *(const f16x4*)(wihp + ks * 16);      // L2-hot stream
        acc[0] = __builtin_amdgcn_mfma_f32_16x16x16f16(a0, w, acc[0], 0, 0, 0);
        acc[1] = __builtin_amdgcn_mfma_f32_16x16x16f16(a1, w, acc[1], 0, 0, 0);
      }
#pragma unroll
      for (int ks = 0; ks < 32; ++ks) {
        const f16x4 a0 = *(const f16x4*)&ht1[l15][ks * 16 + 4 * hi];
        const f16x4 a1 = *(const f16x4*)&ht1[16 + l15][ks * 16 + 4 * hi];
        const f16x4 w  = *(const f16x4*)(whhp + ks * 16);
        acc[0] = __builtin_amdgcn_mfma_f32_16x16x16f16(a0, w, acc[0], 0, 0, 0);
        acc[1] = __builtin_amdgcn_mfma_f32_16x16x16f16(a1, w, acc[1], 0, 0, 0);
      }
      const int col = wv * 16 + l15;
#pragma unroll
      for (int mt = 0; mt < 2; ++mt)
#pragma unroll
        for (int r = 0; r < 4; ++r) gl[mt * 16 + 4 * hi + r][col] = acc[mt][r];
      __syncthreads();

      const float gi = gl[row][j0],       gi1 = gl[row][j0 + 1];
      const float gf = gl[row][32 + j0],  gf1 = gl[row][32 + j0 + 1];
      const float gg = gl[row][64 + j0],  gg1 = gl[row][64 + j0 + 1];
      const float go = gl[row][96 + j0],  go1 = gl[row][96 + j0 + 1];
      c0 = sigf(gf) * c0 + sigf(gi) * tanh_fast(gg);
      c1 = sigf(gf1) * c1 + sigf(gi1) * tanh_fast(gg1);
      const f16 ha = (f16)(sigf(go) * tanh_fast(c0));
      const f16 hb = (f16)(sigf(go1) * tanh_fast(c1));
      unsigned hp = ((unsigned)__builtin_bit_cast(unsigned short, hb) << 16)
                  |  (unsigned)__builtin_bit_cast(unsigned short, ha);
      store_u32_l3(hbuf1 + ((size_t)(t & 1) * B_ + grp * 32 + row) * H_ + sl * 32 + j0, hp);
      wait_vm0();
      __syncthreads();
      if (tid == 0) store_u32_l3(flags + (size_t)(128 + grp * 16 + sl) * 16, (unsigned)(t + 1));
    }
  }
}

// ---------------- MLP head ----------------
__global__ void head_g(const f16* __restrict__ h1, const float* __restrict__ w1,
                       const float* __restrict__ b1, const float* __restrict__ w2,
                       const float* __restrict__ b2, float* __restrict__ out) {
  __shared__ float ft[512];
  __shared__ float hm[256];
  const int b = blockIdx.x, tid = threadIdx.x;
  ft[tid * 2]     = (float)h1[(size_t)b * H_ + tid * 2];
  ft[tid * 2 + 1] = (float)h1[(size_t)b * H_ + tid * 2 + 1];
  __syncthreads();
  {
    float d = b1[tid];
    const float* wr = w1 + (size_t)tid * H_;
#pragma unroll 8
    for (int k = 0; k < H_; ++k) d += ft[k] * wr[k];
    hm[tid] = fmaxf(d, 0.f);
  }
  __syncthreads();
  if (tid < NC_) {
    float d = b2[tid];
    const float* wr = w2 + (size_t)tid * H2_;
#pragma unroll 8
    for (int k = 0; k < H2_; ++k) d += hm[k] * wr[k];
    out[(size_t)b * NC_ + tid] = d;
  }
}

// ---------------- launcher ----------------
extern "C" void kernel_launch(void* const* d_in, const int* in_sizes, int n_in,
                              void* d_out, int out_size, void* d_ws, size_t ws_size,
                              hipStream_t stream) {
  const float* x     = (const float*)d_in[0];
  const float* w_ih0 = (const float*)d_in[1];
  const float* w_hh0 = (const float*)d_in[2];
  const float* b_ih0 = (const float*)d_in[3];
  const float* b_hh0 = (const float*)d_in[4];
  const float* w_ih1 = (const float*)d_in[5];
  const float* w_hh1 = (const float*)d_in[6];
  const float* b_ih1 = (const float*)d_in[7];
  const float* b_hh1 = (const float*)d_in[8];
  const float* w1    = (const float*)d_in[9];
  const float* b1    = (const float*)d_in[10];
  const float* w2    = (const float*)d_in[11];
  const float* b2    = (const float*)d_in[12];
  float* out = (float*)d_out;

  char* p = (char*)d_ws;
  auto alloc = [&](size_t bytes) { char* r = p; p += (bytes + 255) & ~(size_t)255; return r; };
  f16*   h0seq  = (f16*)alloc((size_t)T_ * B_ * H_ * 2);        // 134 MB
  f16*   hbuf1  = (f16*)alloc((size_t)2 * B_ * H_ * 2);
  f16*   x16    = (f16*)alloc((size_t)B_ * T_ * IN_ * 2);
  f16*   wih0h  = (f16*)alloc((size_t)G4_ * IN_ * 2);
  f16*   whh0h  = (f16*)alloc((size_t)G4_ * H_ * 2);
  f16*   wih1h  = (f16*)alloc((size_t)G4_ * H_ * 2);
  f16*   whh1h  = (f16*)alloc((size_t)G4_ * H_ * 2);
  float* bias0c = (float*)alloc(G4_ * 4);
  float* bias1c = (float*)alloc(G4_ * 4);
  unsigned* flags = (unsigned*)alloc(256 * 64);

  hipMemsetAsync(flags, 0, 256 * 64, stream);
  cvt_f32_f16<<<2048, 256, 0, stream>>>(x, x16, B_ * T_ * IN_);
  cvt_f32_f16<<<512, 256, 0, stream>>>(w_ih0, wih0h, G4_ * IN_);
  cvt_f32_f16<<<2048, 256, 0, stream>>>(w_hh0, whh0h, G4_ * H_);
  cvt_f32_f16<<<2048, 256, 0, stream>>>(w_ih1, wih1h, G4_ * H_);
  cvt_f32_f16<<<2048, 256, 0, stream>>>(w_hh1, whh1h, G4_ * H_);
  bias_comb<<<8, 256, 0, stream>>>(b_ih0, b_hh0, bias0c, G4_);
  bias_comb<<<8, 256, 0, stream>>>(b_ih1, b_hh1, bias1c, G4_);

  fused_g<<<256, 512, 0, stream>>>(x16, wih0h, whh0h, wih1h, whh1h,
                                   bias0c, bias1c, h0seq, hbuf1, flags);
  head_g<<<B_, 256, 0, stream>>>(hbuf1 + (size_t)B_ * H_, w1, b1, w2, b2, out);
}

// Round 11
// 3480.181 us; speedup vs baseline: 2.6940x; 2.6940x over previous
//
#include <hip/hip_runtime.h>
#include <stdint.h>

#define B_  256
#define T_  512
#define IN_ 64
#define H_  512
#define G4_ 2048
#define NC_ 64
#define H2_ 256

typedef _Float16 f16;
typedef __attribute__((ext_vector_type(4))) _Float16 f16x4;
typedef __attribute__((ext_vector_type(4))) float    f32x4;
typedef __attribute__((ext_vector_type(2))) unsigned int u32x2;
typedef __attribute__((ext_vector_type(4))) unsigned int u32x4;

__device__ __forceinline__ float sigf(float x) {
  return __builtin_amdgcn_rcpf(1.0f + __expf(-x));
}
__device__ __forceinline__ float tanh_fast(float x) {
  x = fminf(fmaxf(x, -15.f), 15.f);
  const float e = __expf(2.f * x);
  return (e - 1.f) * __builtin_amdgcn_rcpf(e + 1.f);
}
__device__ __forceinline__ unsigned pack2(float a, float b) {
  return ((unsigned)__builtin_bit_cast(unsigned short, (f16)b) << 16)
       |  (unsigned)__builtin_bit_cast(unsigned short, (f16)a);
}
__device__ __forceinline__ float unpk_lo(unsigned u) {
  return (float)__builtin_bit_cast(f16, (unsigned short)(u & 0xffffu));
}
__device__ __forceinline__ float unpk_hi(unsigned u) {
  return (float)__builtin_bit_cast(f16, (unsigned short)(u >> 16));
}

// L3-coherent (cache-bypassing) helpers; wait_vm0 before consuming results.
__device__ __forceinline__ void store_u32_l3(void* p, unsigned v) {
  asm volatile("global_store_dword %0, %1, off sc0 sc1" :: "v"(p), "v"(v) : "memory");
}
__device__ __forceinline__ void store_u32x2_l3(void* p, u32x2 v) {
  asm volatile("global_store_dwordx2 %0, %1, off sc0 sc1" :: "v"(p), "v"(v) : "memory");
}
__device__ __forceinline__ unsigned load_u32_l3(const void* p) {
  unsigned r;
  asm volatile("global_load_dword %0, %1, off sc0 sc1" : "=v"(r) : "v"(p) : "memory");
  return r;
}
__device__ __forceinline__ u32x2 load_u32x2_l3(const void* p) {
  u32x2 r;
  asm volatile("global_load_dwordx2 %0, %1, off sc0 sc1" : "=v"(r) : "v"(p) : "memory");
  return r;
}
__device__ __forceinline__ u32x4 load_u32x4_l3(const void* p) {
  u32x4 r;
  asm volatile("global_load_dwordx4 %0, %1, off sc0 sc1" : "=v"(r) : "v"(p) : "memory");
  return r;
}
__device__ __forceinline__ void wait_vm0() {
  asm volatile("s_waitcnt vmcnt(0)" ::: "memory");
}

// ---------------- prep kernels ----------------
__global__ void cvt_f32_f16(const float* __restrict__ s, f16* __restrict__ d, int n) {
  int i = blockIdx.x * blockDim.x + threadIdx.x;
  int st = gridDim.x * blockDim.x;
  for (; i < n; i += st) d[i] = (f16)s[i];
}

__global__ void bias_comb(const float* __restrict__ a, const float* __restrict__ b,
                          float* __restrict__ d, int n) {
  int i = blockIdx.x * blockDim.x + threadIdx.x;
  if (i < n) d[i] = a[i] + b[i];
}

// ---------------- fused pipelined 2-layer LSTM (round-6 structure) ----------------
// 256 WGs x 512 threads, exactly 1 WG/CU (co-resident).
// role A (bid 0..127):   layer-0 scan, 16 grps x 8 slices; inline gx0 = W_ih0 . x(t)
// role B (bid 128..191): gx1 = W_ih1 . h0(t) + bias1 -> f16 gate-major ring [16][2048][B]
// role C (bid 192..255): layer-1 scan, 8 bgroups(32 rows) x 8 slices(64 h-cols)
// flags: slot i at flags[i*16]; [0,128)=A, [128,192)=B, [192,256)=C; value = steps done.
__global__ __launch_bounds__(512, 2) void fused_g(
    const f16* __restrict__ x16,     // [B][T][64]
    const f16* __restrict__ wih0,    // [2048][64]
    const f16* __restrict__ whh0,    // [2048][512]
    const f16* __restrict__ wih1,    // [2048][512]
    const f16* __restrict__ whh1,    // [2048][512]
    const float* __restrict__ bias0, // [2048]
    const float* __restrict__ bias1, // [2048]
    f16* __restrict__ h0seq,         // [T][B][512]
    f16* __restrict__ gxring,        // [16][2048][B]  f16, gate-major
    f16* __restrict__ hbuf1,         // [2][B][512]
    unsigned* __restrict__ flags) {
  __shared__ __align__(16) unsigned char smem[36352];
  const int bid = blockIdx.x;
  const int tid = threadIdx.x;
  const int lane = tid & 63, wv = tid >> 6;
  const int l15 = lane & 15, hi = lane >> 4;

  if (bid < 128) {
    // ================= role A: layer-0 scan =================
    const int grp = bid >> 3, sl = bid & 7;
    f16 (*xt)[72]   = (f16(*)[72])smem;                        // 2304 B
    f16 (*ht)[532]  = (f16(*)[532])(smem + 2304);              // 17024 B
    float (*gl)[260] = (float(*)[260])(smem + 2304 + 17024);   // 16640 B

    int gidx[2]; f16x4 bhh[2][32]; f16x4 bih[2][4]; float bv[2];
#pragma unroll
    for (int nt = 0; nt < 2; ++nt) {
      const int lg = (wv * 2 + nt) * 16 + l15;
      const int grow = (lg >> 6) * H_ + sl * 64 + (lg & 63);
      gidx[nt] = grow; bv[nt] = bias0[grow];
      const f16* wp = whh0 + (size_t)grow * H_;
#pragma unroll
      for (int ks = 0; ks < 32; ++ks) bhh[nt][ks] = *(const f16x4*)(wp + ks * 16 + 4 * hi);
      const f16* wq = wih0 + (size_t)grow * IN_;
#pragma unroll
      for (int ks = 0; ks < 4; ++ks) bih[nt][ks] = *(const f16x4*)(wq + ks * 16 + 4 * hi);
    }

    const int bl = tid >> 5;
    const int j0 = (tid & 31) * 2;
    float c0 = 0.f, c1 = 0.f;
    const int hrow = tid >> 5, hcol = (tid & 31) * 16;

    for (int t = 0; t < T_; ++t) {
      if (tid < 128) {
        const f16* xs = x16 + ((size_t)(grp * 16 + (tid >> 3)) * T_ + t) * IN_ + (tid & 7) * 8;
        *(uint4*)&xt[tid >> 3][(tid & 7) * 8] = *(const uint4*)xs;
      }
      if (t != 0) {
        const unsigned* pp = flags + (size_t)(grp * 8 + (lane & 7)) * 16;
        const unsigned want = (unsigned)t;
        for (;;) {
          unsigned v = load_u32_l3(pp); wait_vm0();
          if (__all((int)(v >= want))) break;
          __builtin_amdgcn_s_sleep(1);
        }
        const f16* hs = h0seq + ((size_t)(t - 1) * B_ + grp * 16 + hrow) * H_ + hcol;
        u32x4 r0 = load_u32x4_l3(hs);
        u32x4 r1 = load_u32x4_l3(hs + 8);
        wait_vm0();
        __builtin_amdgcn_sched_barrier(0);
        *(u32x4*)&ht[hrow][hcol]     = r0;
        *(u32x4*)&ht[hrow][hcol + 8] = r1;
      } else {
        u32x4 z = {0u, 0u, 0u, 0u};
        *(u32x4*)&ht[hrow][hcol]     = z;
        *(u32x4*)&ht[hrow][hcol + 8] = z;
      }
      __syncthreads();

      f32x4 acc[2];
#pragma unroll
      for (int nt = 0; nt < 2; ++nt) { acc[nt][0] = bv[nt]; acc[nt][1] = bv[nt]; acc[nt][2] = bv[nt]; acc[nt][3] = bv[nt]; }
#pragma unroll
      for (int ks = 0; ks < 4; ++ks) {
        const f16x4 a = *(const f16x4*)&xt[l15][ks * 16 + 4 * hi];
        acc[0] = __builtin_amdgcn_mfma_f32_16x16x16f16(a, bih[0][ks], acc[0], 0, 0, 0);
        acc[1] = __builtin_amdgcn_mfma_f32_16x16x16f16(a, bih[1][ks], acc[1], 0, 0, 0);
      }
#pragma unroll
      for (int ks = 0; ks < 32; ++ks) {
        const f16x4 a = *(const f16x4*)&ht[l15][ks * 16 + 4 * hi];
        acc[0] = __builtin_amdgcn_mfma_f32_16x16x16f16(a, bhh[0][ks], acc[0], 0, 0, 0);
        acc[1] = __builtin_amdgcn_mfma_f32_16x16x16f16(a, bhh[1][ks], acc[1], 0, 0, 0);
      }
#pragma unroll
      for (int nt = 0; nt < 2; ++nt) {
        const int col = (wv * 2 + nt) * 16 + l15;
#pragma unroll
        for (int r = 0; r < 4; ++r) gl[4 * hi + r][col] = acc[nt][r];
      }
      __syncthreads();

      const float gi = gl[bl][j0],        gi1 = gl[bl][j0 + 1];
      const float gf = gl[bl][64 + j0],   gf1 = gl[bl][64 + j0 + 1];
      const float gg = gl[bl][128 + j0],  gg1 = gl[bl][128 + j0 + 1];
      const float go = gl[bl][192 + j0],  go1 = gl[bl][192 + j0 + 1];
      c0 = sigf(gf) * c0 + sigf(gi) * tanh_fast(gg);
      c1 = sigf(gf1) * c1 + sigf(gi1) * tanh_fast(gg1);
      const f16 h0h = (f16)(sigf(go) * tanh_fast(c0));
      const f16 h1h = (f16)(sigf(go1) * tanh_fast(c1));
      unsigned hp = ((unsigned)__builtin_bit_cast(unsigned short, h1h) << 16)
                  |  (unsigned)__builtin_bit_cast(unsigned short, h0h);
      store_u32_l3(h0seq + ((size_t)t * B_ + grp * 16 + bl) * H_ + sl * 64 + j0, hp);
      wait_vm0();
      __syncthreads();
      if (tid == 0) store_u32_l3(flags + (size_t)(grp * 8 + sl) * 16, (unsigned)(t + 1));
    }

  } else if (bid < 192) {
    // ================= role B: gx1 producer (f16 gate-major ring) =================
    const int bg = (bid - 128) >> 3, slB = (bid - 128) & 7;
    f16 (*ht)[532] = (f16(*)[532])smem;                        // 32 rows

    int gidx[2]; f16x4 bih[2][32]; float bv[2];
#pragma unroll
    for (int nt = 0; nt < 2; ++nt) {
      const int grow = slB * 256 + (wv * 2 + nt) * 16 + l15;
      gidx[nt] = grow; bv[nt] = bias1[grow];
      const f16* wp = wih1 + (size_t)grow * H_;
#pragma unroll
      for (int ks = 0; ks < 32; ++ks) bih[nt][ks] = *(const f16x4*)(wp + ks * 16 + 4 * hi);
    }
    const int hrow = tid >> 4, hcol = (tid & 15) * 32;         // 32 rows x 16 thr

    for (int t = 0; t < T_; ++t) {
      {
        const bool isC = (lane >= 16 && lane < 24);
        const unsigned wantC = (t >= 16) ? (unsigned)(t - 15) : 0u;
        const int slot = isC ? (192 + bg * 8 + (lane - 16)) : (bg * 16 + (lane & 15));
        const unsigned want = isC ? wantC : (unsigned)(t + 1);
        const unsigned* pp = flags + (size_t)slot * 16;
        for (;;) {
          unsigned v = load_u32_l3(pp); wait_vm0();
          if (__all((int)(v >= want))) break;
          __builtin_amdgcn_s_sleep(1);
        }
      }
      {
        const f16* hs = h0seq + ((size_t)t * B_ + bg * 32 + hrow) * H_ + hcol;
        u32x4 r0 = load_u32x4_l3(hs);
        u32x4 r1 = load_u32x4_l3(hs + 8);
        u32x4 r2 = load_u32x4_l3(hs + 16);
        u32x4 r3 = load_u32x4_l3(hs + 24);
        wait_vm0();
        __builtin_amdgcn_sched_barrier(0);
        *(u32x4*)&ht[hrow][hcol]      = r0;
        *(u32x4*)&ht[hrow][hcol + 8]  = r1;
        *(u32x4*)&ht[hrow][hcol + 16] = r2;
        *(u32x4*)&ht[hrow][hcol + 24] = r3;
      }
      __syncthreads();

      f32x4 acc[2][2] = {};
#pragma unroll
      for (int ks = 0; ks < 32; ++ks) {
        const f16x4 a0 = *(const f16x4*)&ht[l15][ks * 16 + 4 * hi];
        const f16x4 a1 = *(const f16x4*)&ht[16 + l15][ks * 16 + 4 * hi];
        acc[0][0] = __builtin_amdgcn_mfma_f32_16x16x16f16(a0, bih[0][ks], acc[0][0], 0, 0, 0);
        acc[0][1] = __builtin_amdgcn_mfma_f32_16x16x16f16(a0, bih[1][ks], acc[0][1], 0, 0, 0);
        acc[1][0] = __builtin_amdgcn_mfma_f32_16x16x16f16(a1, bih[0][ks], acc[1][0], 0, 0, 0);
        acc[1][1] = __builtin_amdgcn_mfma_f32_16x16x16f16(a1, bih[1][ks], acc[1][1], 0, 0, 0);
      }
      // store: gate-major [gate][B]; 4 consecutive rows -> one 8B store
      f16* gp = gxring + (size_t)(t & 15) * G4_ * B_;
#pragma unroll
      for (int mt = 0; mt < 2; ++mt)
#pragma unroll
        for (int nt = 0; nt < 2; ++nt) {
          u32x2 pay;
          pay.x = pack2(acc[mt][nt][0] + bv[nt], acc[mt][nt][1] + bv[nt]);
          pay.y = pack2(acc[mt][nt][2] + bv[nt], acc[mt][nt][3] + bv[nt]);
          store_u32x2_l3(gp + (size_t)gidx[nt] * B_ + bg * 32 + mt * 16 + 4 * hi, pay);
        }
      wait_vm0();
      __syncthreads();
      if (tid == 0) store_u32_l3(flags + (size_t)(128 + bg * 8 + slB) * 16, (unsigned)(t + 1));
    }

  } else {
    // ================= role C: layer-1 scan =================
    const int bg = (bid - 192) >> 3, slC = (bid - 192) & 7;
    f16 (*ht)[532]   = (f16(*)[532])smem;                      // 32 rows (union w/ gl)
    float (*gl)[260] = (float(*)[260])smem;

    int gidx[2]; f16x4 bhh[2][32];
#pragma unroll
    for (int nt = 0; nt < 2; ++nt) {
      const int lg = (wv * 2 + nt) * 16 + l15;
      const int grow = (lg >> 6) * H_ + slC * 64 + (lg & 63);
      gidx[nt] = grow;
      const f16* wp = whh1 + (size_t)grow * H_;
#pragma unroll
      for (int ks = 0; ks < 32; ++ks) bhh[nt][ks] = *(const f16x4*)(wp + ks * 16 + 4 * hi);
    }
    const int r0row = tid >> 5;              // own cells: rows r0row, r0row+16
    const int j0 = (tid & 31) * 2;
    float c00 = 0.f, c01 = 0.f, c10 = 0.f, c11 = 0.f;
    const int hrow = tid >> 4, hcol = (tid & 15) * 32;

    for (int t = 0; t < T_; ++t) {
      {
        const bool isOwn = (lane >= 8 && lane < 16);
        const unsigned wantOwn = (t >= 1) ? (unsigned)t : 0u;
        const int slot = isOwn ? (192 + bg * 8 + (lane - 8)) : (128 + bg * 8 + (lane & 7));
        const unsigned want = isOwn ? wantOwn : (unsigned)(t + 1);
        const unsigned* pp = flags + (size_t)slot * 16;
        for (;;) {
          unsigned v = load_u32_l3(pp); wait_vm0();
          if (__all((int)(v >= want))) break;
          __builtin_amdgcn_s_sleep(1);
        }
      }
      // issue gx loads (4 x dwordx2, contiguous) + h1 stage loads, one drain
      u32x2 gxv[2][2];
      const f16* gp = gxring + (size_t)(t & 15) * G4_ * B_;
#pragma unroll
      for (int mt = 0; mt < 2; ++mt)
#pragma unroll
        for (int nt = 0; nt < 2; ++nt)
          gxv[mt][nt] = load_u32x2_l3(gp + (size_t)gidx[nt] * B_ + bg * 32 + mt * 16 + 4 * hi);
      if (t != 0) {
        const f16* hs = hbuf1 + ((size_t)((t - 1) & 1) * B_ + bg * 32 + hrow) * H_ + hcol;
        u32x4 r0 = load_u32x4_l3(hs);
        u32x4 r1 = load_u32x4_l3(hs + 8);
        u32x4 r2 = load_u32x4_l3(hs + 16);
        u32x4 r3 = load_u32x4_l3(hs + 24);
        wait_vm0();
        __builtin_amdgcn_sched_barrier(0);
        *(u32x4*)&ht[hrow][hcol]      = r0;
        *(u32x4*)&ht[hrow][hcol + 8]  = r1;
        *(u32x4*)&ht[hrow][hcol + 16] = r2;
        *(u32x4*)&ht[hrow][hcol + 24] = r3;
      } else {
        wait_vm0();
        u32x4 z = {0u, 0u, 0u, 0u};
        *(u32x4*)&ht[hrow][hcol]      = z;
        *(u32x4*)&ht[hrow][hcol + 8]  = z;
        *(u32x4*)&ht[hrow][hcol + 16] = z;
        *(u32x4*)&ht[hrow][hcol + 24] = z;
      }
      __syncthreads();

      f32x4 acc[2][2];
#pragma unroll
      for (int mt = 0; mt < 2; ++mt)
#pragma unroll
        for (int nt = 0; nt < 2; ++nt) {
          const unsigned ux = gxv[mt][nt].x, uy = gxv[mt][nt].y;
          const float v0 = unpk_lo(ux), v1 = unpk_hi(ux);
          const float v2 = unpk_lo(uy), v3 = unpk_hi(uy);
          acc[mt][nt][0] = v0; acc[mt][nt][1] = v1;
          acc[mt][nt][2] = v2; acc[mt][nt][3] = v3;
        }
#pragma unroll
      for (int ks = 0; ks < 32; ++ks) {
        const f16x4 a0 = *(const f16x4*)&ht[l15][ks * 16 + 4 * hi];
        const f16x4 a1 = *(const f16x4*)&ht[16 + l15][ks * 16 + 4 * hi];
        acc[0][0] = __builtin_amdgcn_mfma_f32_16x16x16f16(a0, bhh[0][ks], acc[0][0], 0, 0, 0);
        acc[0][1] = __builtin_amdgcn_mfma_f32_16x16x16f16(a0, bhh[1][ks], acc[0][1], 0, 0, 0);
        acc[1][0] = __builtin_amdgcn_mfma_f32_16x16x16f16(a1, bhh[0][ks], acc[1][0], 0, 0, 0);
        acc[1][1] = __builtin_amdgcn_mfma_f32_16x16x16f16(a1, bhh[1][ks], acc[1][1], 0, 0, 0);
      }
      __syncthreads();   // all ht reads done before gl overwrites the union
#pragma unroll
      for (int mt = 0; mt < 2; ++mt)
#pragma unroll
        for (int nt = 0; nt < 2; ++nt) {
          const int col = (wv * 2 + nt) * 16 + l15;
#pragma unroll
          for (int r = 0; r < 4; ++r) gl[mt * 16 + 4 * hi + r][col] = acc[mt][nt][r];
        }
      __syncthreads();

      const int cur = t & 1;
#pragma unroll
      for (int half = 0; half < 2; ++half) {
        const int row = r0row + half * 16;
        const float gi = gl[row][j0],        gi1 = gl[row][j0 + 1];
        const float gf = gl[row][64 + j0],   gf1 = gl[row][64 + j0 + 1];
        const float gg = gl[row][128 + j0],  gg1 = gl[row][128 + j0 + 1];
        const float go = gl[row][192 + j0],  go1 = gl[row][192 + j0 + 1];
        float& ca = half ? c10 : c00;
        float& cb = half ? c11 : c01;
        ca = sigf(gf) * ca + sigf(gi) * tanh_fast(gg);
        cb = sigf(gf1) * cb + sigf(gi1) * tanh_fast(gg1);
        const f16 ha = (f16)(sigf(go) * tanh_fast(ca));
        const f16 hb = (f16)(sigf(go1) * tanh_fast(cb));
        unsigned hp = ((unsigned)__builtin_bit_cast(unsigned short, hb) << 16)
                    |  (unsigned)__builtin_bit_cast(unsigned short, ha);
        store_u32_l3(hbuf1 + ((size_t)cur * B_ + bg * 32 + row) * H_ + slC * 64 + j0, hp);
      }
      wait_vm0();
      __syncthreads();
      if (tid == 0) store_u32_l3(flags + (size_t)(192 + bg * 8 + slC) * 16, (unsigned)(t + 1));
    }
  }
}

// ---------------- MLP head ----------------
__global__ void head_g(const f16* __restrict__ h1, const float* __restrict__ w1,
                       const float* __restrict__ b1, const float* __restrict__ w2,
                       const float* __restrict__ b2, float* __restrict__ out) {
  __shared__ float ft[512];
  __shared__ float hm[256];
  const int b = blockIdx.x, tid = threadIdx.x;
  ft[tid * 2]     = (float)h1[(size_t)b * H_ + tid * 2];
  ft[tid * 2 + 1] = (float)h1[(size_t)b * H_ + tid * 2 + 1];
  __syncthreads();
  {
    float d = b1[tid];
    const float* wr = w1 + (size_t)tid * H_;
#pragma unroll 8
    for (int k = 0; k < H_; ++k) d += ft[k] * wr[k];
    hm[tid] = fmaxf(d, 0.f);
  }
  __syncthreads();
  if (tid < NC_) {
    float d = b2[tid];
    const float* wr = w2 + (size_t)tid * H2_;
#pragma unroll 8
    for (int k = 0; k < H2_; ++k) d += hm[k] * wr[k];
    out[(size_t)b * NC_ + tid] = d;
  }
}

// ---------------- launcher ----------------
extern "C" void kernel_launch(void* const* d_in, const int* in_sizes, int n_in,
                              void* d_out, int out_size, void* d_ws, size_t ws_size,
                              hipStream_t stream) {
  const float* x     = (const float*)d_in[0];
  const float* w_ih0 = (const float*)d_in[1];
  const float* w_hh0 = (const float*)d_in[2];
  const float* b_ih0 = (const float*)d_in[3];
  const float* b_hh0 = (const float*)d_in[4];
  const float* w_ih1 = (const float*)d_in[5];
  const float* w_hh1 = (const float*)d_in[6];
  const float* b_ih1 = (const float*)d_in[7];
  const float* b_hh1 = (const float*)d_in[8];
  const float* w1    = (const float*)d_in[9];
  const float* b1    = (const float*)d_in[10];
  const float* w2    = (const float*)d_in[11];
  const float* b2    = (const float*)d_in[12];
  float* out = (float*)d_out;

  char* p = (char*)d_ws;
  auto alloc = [&](size_t bytes) { char* r = p; p += (bytes + 255) & ~(size_t)255; return r; };
  f16*   h0seq  = (f16*)alloc((size_t)T_ * B_ * H_ * 2);        // 134 MB
  f16*   gxring = (f16*)alloc((size_t)16 * G4_ * B_ * 2);       // 16.8 MB, gate-major
  f16*   hbuf1  = (f16*)alloc((size_t)2 * B_ * H_ * 2);
  f16*   x16    = (f16*)alloc((size_t)B_ * T_ * IN_ * 2);
  f16*   wih0h  = (f16*)alloc((size_t)G4_ * IN_ * 2);
  f16*   whh0h  = (f16*)alloc((size_t)G4_ * H_ * 2);
  f16*   wih1h  = (f16*)alloc((size_t)G4_ * H_ * 2);
  f16*   whh1h  = (f16*)alloc((size_t)G4_ * H_ * 2);
  float* bias0c = (float*)alloc(G4_ * 4);
  float* bias1c = (float*)alloc(G4_ * 4);
  unsigned* flags = (unsigned*)alloc(256 * 64);

  hipMemsetAsync(flags, 0, 256 * 64, stream);
  cvt_f32_f16<<<2048, 256, 0, stream>>>(x, x16, B_ * T_ * IN_);
  cvt_f32_f16<<<512, 256, 0, stream>>>(w_ih0, wih0h, G4_ * IN_);
  cvt_f32_f16<<<2048, 256, 0, stream>>>(w_hh0, whh0h, G4_ * H_);
  cvt_f32_f16<<<2048, 256, 0, stream>>>(w_ih1, wih1h, G4_ * H_);
  cvt_f32_f16<<<2048, 256, 0, stream>>>(w_hh1, whh1h, G4_ * H_);
  bias_comb<<<8, 256, 0, stream>>>(b_ih0, b_hh0, bias0c, G4_);
  bias_comb<<<8, 256, 0, stream>>>(b_ih1, b_hh1, bias1c, G4_);

  fused_g<<<256, 512, 0, stream>>>(x16, wih0h, whh0h, wih1h, whh1h,
                                   bias0c, bias1c, h0seq, gxring, hbuf1, flags);
  head_g<<<B_, 256, 0, stream>>>(hbuf1 + (size_t)B_ * H_, w1, b1, w2, b2, out);
}

// Round 12
// 3434.243 us; speedup vs baseline: 2.7301x; 1.0134x over previous
//
#include <hip/hip_runtime.h>
#include <stdint.h>

#define B_  256
#define T_  512
#define IN_ 64
#define H_  512
#define G4_ 2048
#define NC_ 64
#define H2_ 256

typedef _Float16 f16;
typedef __attribute__((ext_vector_type(4))) _Float16 f16x4;
typedef __attribute__((ext_vector_type(4))) float    f32x4;
typedef __attribute__((ext_vector_type(2))) unsigned int u32x2;
typedef __attribute__((ext_vector_type(4))) unsigned int u32x4;

__device__ __forceinline__ float sigf(float x) {
  return __builtin_amdgcn_rcpf(1.0f + __expf(-x));
}
__device__ __forceinline__ float tanh_fast(float x) {
  x = fminf(fmaxf(x, -15.f), 15.f);
  const float e = __expf(2.f * x);
  return (e - 1.f) * __builtin_amdgcn_rcpf(e + 1.f);
}
__device__ __forceinline__ unsigned pack2(float a, float b) {
  return ((unsigned)__builtin_bit_cast(unsigned short, (f16)b) << 16)
       |  (unsigned)__builtin_bit_cast(unsigned short, (f16)a);
}
__device__ __forceinline__ float unpk_lo(unsigned u) {
  return (float)__builtin_bit_cast(f16, (unsigned short)(u & 0xffffu));
}
__device__ __forceinline__ float unpk_hi(unsigned u) {
  return (float)__builtin_bit_cast(f16, (unsigned short)(u >> 16));
}
// Opacity pin: makes the loaded value opaque so the compiler cannot
// rematerialize the load inside the t-loop — forces register residency.
__device__ __forceinline__ void pin(f16x4& v) {
  asm volatile("" : "+v"(v));
}

// L3-coherent (cache-bypassing) helpers; wait_vm0 before consuming results.
__device__ __forceinline__ void store_u32_l3(void* p, unsigned v) {
  asm volatile("global_store_dword %0, %1, off sc0 sc1" :: "v"(p), "v"(v) : "memory");
}
__device__ __forceinline__ void store_u32x2_l3(void* p, u32x2 v) {
  asm volatile("global_store_dwordx2 %0, %1, off sc0 sc1" :: "v"(p), "v"(v) : "memory");
}
__device__ __forceinline__ unsigned load_u32_l3(const void* p) {
  unsigned r;
  asm volatile("global_load_dword %0, %1, off sc0 sc1" : "=v"(r) : "v"(p) : "memory");
  return r;
}
__device__ __forceinline__ u32x2 load_u32x2_l3(const void* p) {
  u32x2 r;
  asm volatile("global_load_dwordx2 %0, %1, off sc0 sc1" : "=v"(r) : "v"(p) : "memory");
  return r;
}
__device__ __forceinline__ u32x4 load_u32x4_l3(const void* p) {
  u32x4 r;
  asm volatile("global_load_dwordx4 %0, %1, off sc0 sc1" : "=v"(r) : "v"(p) : "memory");
  return r;
}
__device__ __forceinline__ void wait_vm0() {
  asm volatile("s_waitcnt vmcnt(0)" ::: "memory");
}

// ---------------- prep kernels ----------------
__global__ void cvt_f32_f16(const float* __restrict__ s, f16* __restrict__ d, int n) {
  int i = blockIdx.x * blockDim.x + threadIdx.x;
  int st = gridDim.x * blockDim.x;
  for (; i < n; i += st) d[i] = (f16)s[i];
}

__global__ void bias_comb(const float* __restrict__ a, const float* __restrict__ b,
                          float* __restrict__ d, int n) {
  int i = blockIdx.x * blockDim.x + threadIdx.x;
  if (i < n) d[i] = a[i] + b[i];
}

// ---------------- fused pipelined 2-layer LSTM (round-6 structure) ----------------
// 256 WGs x 512 threads, exactly 1 WG/CU (co-resident).
// role A (bid 0..127):   layer-0 scan, 16 grps x 8 slices; inline gx0 = W_ih0 . x(t)
// role B (bid 128..191): gx1 = W_ih1 . h0(t) + bias1 -> f16 gate-major ring [16][2048][B]
// role C (bid 192..255): layer-1 scan, 8 bgroups(32 rows) x 8 slices(64 h-cols)
// Weight fragments PINNED in VGPRs (asm opacity) -> no per-step L2 weight stream.
// flags: slot i at flags[i*16]; [0,128)=A, [128,192)=B, [192,256)=C; value = steps done.
__global__ __launch_bounds__(512, 2) void fused_g(
    const f16* __restrict__ x16,     // [B][T][64]
    const f16* __restrict__ wih0,    // [2048][64]
    const f16* __restrict__ whh0,    // [2048][512]
    const f16* __restrict__ wih1,    // [2048][512]
    const f16* __restrict__ whh1,    // [2048][512]
    const float* __restrict__ bias0, // [2048]
    const float* __restrict__ bias1, // [2048]
    f16* __restrict__ h0seq,         // [T][B][512]
    f16* __restrict__ gxring,        // [16][2048][B]  f16, gate-major
    f16* __restrict__ hbuf1,         // [2][B][512]
    unsigned* __restrict__ flags) {
  __shared__ __align__(16) unsigned char smem[36352];
  const int bid = blockIdx.x;
  const int tid = threadIdx.x;
  const int lane = tid & 63, wv = tid >> 6;
  const int l15 = lane & 15, hi = lane >> 4;

  if (bid < 128) {
    // ================= role A: layer-0 scan =================
    const int grp = bid >> 3, sl = bid & 7;
    f16 (*xt)[72]   = (f16(*)[72])smem;                        // 2304 B
    f16 (*ht)[532]  = (f16(*)[532])(smem + 2304);              // 17024 B
    float (*gl)[260] = (float(*)[260])(smem + 2304 + 17024);   // 16640 B

    int gidx[2]; f16x4 bhh[2][32]; f16x4 bih[2][4]; float bv[2];
#pragma unroll
    for (int nt = 0; nt < 2; ++nt) {
      const int lg = (wv * 2 + nt) * 16 + l15;
      const int grow = (lg >> 6) * H_ + sl * 64 + (lg & 63);
      gidx[nt] = grow; bv[nt] = bias0[grow];
      const f16* wp = whh0 + (size_t)grow * H_;
#pragma unroll
      for (int ks = 0; ks < 32; ++ks) { bhh[nt][ks] = *(const f16x4*)(wp + ks * 16 + 4 * hi); pin(bhh[nt][ks]); }
      const f16* wq = wih0 + (size_t)grow * IN_;
#pragma unroll
      for (int ks = 0; ks < 4; ++ks) { bih[nt][ks] = *(const f16x4*)(wq + ks * 16 + 4 * hi); pin(bih[nt][ks]); }
    }

    const int bl = tid >> 5;
    const int j0 = (tid & 31) * 2;
    float c0 = 0.f, c1 = 0.f;
    const int hrow = tid >> 5, hcol = (tid & 31) * 16;

    for (int t = 0; t < T_; ++t) {
      if (tid < 128) {
        const f16* xs = x16 + ((size_t)(grp * 16 + (tid >> 3)) * T_ + t) * IN_ + (tid & 7) * 8;
        *(uint4*)&xt[tid >> 3][(tid & 7) * 8] = *(const uint4*)xs;
      }
      if (t != 0) {
        const unsigned* pp = flags + (size_t)(grp * 8 + (lane & 7)) * 16;
        const unsigned want = (unsigned)t;
        for (;;) {
          unsigned v = load_u32_l3(pp); wait_vm0();
          if (__all((int)(v >= want))) break;
          __builtin_amdgcn_s_sleep(1);
        }
        const f16* hs = h0seq + ((size_t)(t - 1) * B_ + grp * 16 + hrow) * H_ + hcol;
        u32x4 r0 = load_u32x4_l3(hs);
        u32x4 r1 = load_u32x4_l3(hs + 8);
        wait_vm0();
        __builtin_amdgcn_sched_barrier(0);
        *(u32x4*)&ht[hrow][hcol]     = r0;
        *(u32x4*)&ht[hrow][hcol + 8] = r1;
      } else {
        u32x4 z = {0u, 0u, 0u, 0u};
        *(u32x4*)&ht[hrow][hcol]     = z;
        *(u32x4*)&ht[hrow][hcol + 8] = z;
      }
      __syncthreads();

      f32x4 acc[2];
#pragma unroll
      for (int nt = 0; nt < 2; ++nt) { acc[nt][0] = bv[nt]; acc[nt][1] = bv[nt]; acc[nt][2] = bv[nt]; acc[nt][3] = bv[nt]; }
#pragma unroll
      for (int ks = 0; ks < 4; ++ks) {
        const f16x4 a = *(const f16x4*)&xt[l15][ks * 16 + 4 * hi];
        acc[0] = __builtin_amdgcn_mfma_f32_16x16x16f16(a, bih[0][ks], acc[0], 0, 0, 0);
        acc[1] = __builtin_amdgcn_mfma_f32_16x16x16f16(a, bih[1][ks], acc[1], 0, 0, 0);
      }
#pragma unroll
      for (int ks = 0; ks < 32; ++ks) {
        const f16x4 a = *(const f16x4*)&ht[l15][ks * 16 + 4 * hi];
        acc[0] = __builtin_amdgcn_mfma_f32_16x16x16f16(a, bhh[0][ks], acc[0], 0, 0, 0);
        acc[1] = __builtin_amdgcn_mfma_f32_16x16x16f16(a, bhh[1][ks], acc[1], 0, 0, 0);
      }
#pragma unroll
      for (int nt = 0; nt < 2; ++nt) {
        const int col = (wv * 2 + nt) * 16 + l15;
#pragma unroll
        for (int r = 0; r < 4; ++r) gl[4 * hi + r][col] = acc[nt][r];
      }
      __syncthreads();

      const float gi = gl[bl][j0],        gi1 = gl[bl][j0 + 1];
      const float gf = gl[bl][64 + j0],   gf1 = gl[bl][64 + j0 + 1];
      const float gg = gl[bl][128 + j0],  gg1 = gl[bl][128 + j0 + 1];
      const float go = gl[bl][192 + j0],  go1 = gl[bl][192 + j0 + 1];
      c0 = sigf(gf) * c0 + sigf(gi) * tanh_fast(gg);
      c1 = sigf(gf1) * c1 + sigf(gi1) * tanh_fast(gg1);
      const f16 h0h = (f16)(sigf(go) * tanh_fast(c0));
      const f16 h1h = (f16)(sigf(go1) * tanh_fast(c1));
      unsigned hp = ((unsigned)__builtin_bit_cast(unsigned short, h1h) << 16)
                  |  (unsigned)__builtin_bit_cast(unsigned short, h0h);
      store_u32_l3(h0seq + ((size_t)t * B_ + grp * 16 + bl) * H_ + sl * 64 + j0, hp);
      wait_vm0();
      __syncthreads();
      if (tid == 0) store_u32_l3(flags + (size_t)(grp * 8 + sl) * 16, (unsigned)(t + 1));
    }

  } else if (bid < 192) {
    // ================= role B: gx1 producer (f16 gate-major ring) =================
    const int bg = (bid - 128) >> 3, slB = (bid - 128) & 7;
    f16 (*ht)[532] = (f16(*)[532])smem;                        // 32 rows

    int gidx[2]; f16x4 bih[2][32]; float bv[2];
#pragma unroll
    for (int nt = 0; nt < 2; ++nt) {
      const int grow = slB * 256 + (wv * 2 + nt) * 16 + l15;
      gidx[nt] = grow; bv[nt] = bias1[grow];
      const f16* wp = wih1 + (size_t)grow * H_;
#pragma unroll
      for (int ks = 0; ks < 32; ++ks) { bih[nt][ks] = *(const f16x4*)(wp + ks * 16 + 4 * hi); pin(bih[nt][ks]); }
    }
    const int hrow = tid >> 4, hcol = (tid & 15) * 32;         // 32 rows x 16 thr

    for (int t = 0; t < T_; ++t) {
      {
        const bool isC = (lane >= 16 && lane < 24);
        const unsigned wantC = (t >= 16) ? (unsigned)(t - 15) : 0u;
        const int slot = isC ? (192 + bg * 8 + (lane - 16)) : (bg * 16 + (lane & 15));
        const unsigned want = isC ? wantC : (unsigned)(t + 1);
        const unsigned* pp = flags + (size_t)slot * 16;
        for (;;) {
          unsigned v = load_u32_l3(pp); wait_vm0();
          if (__all((int)(v >= want))) break;
          __builtin_amdgcn_s_sleep(1);
        }
      }
      {
        const f16* hs = h0seq + ((size_t)t * B_ + bg * 32 + hrow) * H_ + hcol;
        u32x4 r0 = load_u32x4_l3(hs);
        u32x4 r1 = load_u32x4_l3(hs + 8);
        u32x4 r2 = load_u32x4_l3(hs + 16);
        u32x4 r3 = load_u32x4_l3(hs + 24);
        wait_vm0();
        __builtin_amdgcn_sched_barrier(0);
        *(u32x4*)&ht[hrow][hcol]      = r0;
        *(u32x4*)&ht[hrow][hcol + 8]  = r1;
        *(u32x4*)&ht[hrow][hcol + 16] = r2;
        *(u32x4*)&ht[hrow][hcol + 24] = r3;
      }
      __syncthreads();

      f32x4 acc[2][2] = {};
#pragma unroll
      for (int ks = 0; ks < 32; ++ks) {
        const f16x4 a0 = *(const f16x4*)&ht[l15][ks * 16 + 4 * hi];
        const f16x4 a1 = *(const f16x4*)&ht[16 + l15][ks * 16 + 4 * hi];
        acc[0][0] = __builtin_amdgcn_mfma_f32_16x16x16f16(a0, bih[0][ks], acc[0][0], 0, 0, 0);
        acc[0][1] = __builtin_amdgcn_mfma_f32_16x16x16f16(a0, bih[1][ks], acc[0][1], 0, 0, 0);
        acc[1][0] = __builtin_amdgcn_mfma_f32_16x16x16f16(a1, bih[0][ks], acc[1][0], 0, 0, 0);
        acc[1][1] = __builtin_amdgcn_mfma_f32_16x16x16f16(a1, bih[1][ks], acc[1][1], 0, 0, 0);
      }
      // store: gate-major [gate][B]; 4 consecutive rows -> one 8B store
      f16* gp = gxring + (size_t)(t & 15) * G4_ * B_;
#pragma unroll
      for (int mt = 0; mt < 2; ++mt)
#pragma unroll
        for (int nt = 0; nt < 2; ++nt) {
          u32x2 pay;
          pay.x = pack2(acc[mt][nt][0] + bv[nt], acc[mt][nt][1] + bv[nt]);
          pay.y = pack2(acc[mt][nt][2] + bv[nt], acc[mt][nt][3] + bv[nt]);
          store_u32x2_l3(gp + (size_t)gidx[nt] * B_ + bg * 32 + mt * 16 + 4 * hi, pay);
        }
      wait_vm0();
      __syncthreads();
      if (tid == 0) store_u32_l3(flags + (size_t)(128 + bg * 8 + slB) * 16, (unsigned)(t + 1));
    }

  } else {
    // ================= role C: layer-1 scan =================
    const int bg = (bid - 192) >> 3, slC = (bid - 192) & 7;
    f16 (*ht)[532]   = (f16(*)[532])smem;                      // 32 rows (union w/ gl)
    float (*gl)[260] = (float(*)[260])smem;

    int gidx[2]; f16x4 bhh[2][32];
#pragma unroll
    for (int nt = 0; nt < 2; ++nt) {
      const int lg = (wv * 2 + nt) * 16 + l15;
      const int grow = (lg >> 6) * H_ + slC * 64 + (lg & 63);
      gidx[nt] = grow;
      const f16* wp = whh1 + (size_t)grow * H_;
#pragma unroll
      for (int ks = 0; ks < 32; ++ks) { bhh[nt][ks] = *(const f16x4*)(wp + ks * 16 + 4 * hi); pin(bhh[nt][ks]); }
    }
    const int r0row = tid >> 5;              // own cells: rows r0row, r0row+16
    const int j0 = (tid & 31) * 2;
    float c00 = 0.f, c01 = 0.f, c10 = 0.f, c11 = 0.f;
    const int hrow = tid >> 4, hcol = (tid & 15) * 32;

    for (int t = 0; t < T_; ++t) {
      {
        const bool isOwn = (lane >= 8 && lane < 16);
        const unsigned wantOwn = (t >= 1) ? (unsigned)t : 0u;
        const int slot = isOwn ? (192 + bg * 8 + (lane - 8)) : (128 + bg * 8 + (lane & 7));
        const unsigned want = isOwn ? wantOwn : (unsigned)(t + 1);
        const unsigned* pp = flags + (size_t)slot * 16;
        for (;;) {
          unsigned v = load_u32_l3(pp); wait_vm0();
          if (__all((int)(v >= want))) break;
          __builtin_amdgcn_s_sleep(1);
        }
      }
      // issue gx loads (4 x dwordx2, contiguous) + h1 stage loads, one drain
      u32x2 gxv[2][2];
      const f16* gp = gxring + (size_t)(t & 15) * G4_ * B_;
#pragma unroll
      for (int mt = 0; mt < 2; ++mt)
#pragma unroll
        for (int nt = 0; nt < 2; ++nt)
          gxv[mt][nt] = load_u32x2_l3(gp + (size_t)gidx[nt] * B_ + bg * 32 + mt * 16 + 4 * hi);
      if (t != 0) {
        const f16* hs = hbuf1 + ((size_t)((t - 1) & 1) * B_ + bg * 32 + hrow) * H_ + hcol;
        u32x4 r0 = load_u32x4_l3(hs);
        u32x4 r1 = load_u32x4_l3(hs + 8);
        u32x4 r2 = load_u32x4_l3(hs + 16);
        u32x4 r3 = load_u32x4_l3(hs + 24);
        wait_vm0();
        __builtin_amdgcn_sched_barrier(0);
        *(u32x4*)&ht[hrow][hcol]      = r0;
        *(u32x4*)&ht[hrow][hcol + 8]  = r1;
        *(u32x4*)&ht[hrow][hcol + 16] = r2;
        *(u32x4*)&ht[hrow][hcol + 24] = r3;
      } else {
        wait_vm0();
        u32x4 z = {0u, 0u, 0u, 0u};
        *(u32x4*)&ht[hrow][hcol]      = z;
        *(u32x4*)&ht[hrow][hcol + 8]  = z;
        *(u32x4*)&ht[hrow][hcol + 16] = z;
        *(u32x4*)&ht[hrow][hcol + 24] = z;
      }
      __syncthreads();

      f32x4 acc[2][2];
#pragma unroll
      for (int mt = 0; mt < 2; ++mt)
#pragma unroll
        for (int nt = 0; nt < 2; ++nt) {
          const unsigned ux = gxv[mt][nt].x, uy = gxv[mt][nt].y;
          const float v0 = unpk_lo(ux), v1 = unpk_hi(ux);
          const float v2 = unpk_lo(uy), v3 = unpk_hi(uy);
          acc[mt][nt][0] = v0; acc[mt][nt][1] = v1;
          acc[mt][nt][2] = v2; acc[mt][nt][3] = v3;
        }
#pragma unroll
      for (int ks = 0; ks < 32; ++ks) {
        const f16x4 a0 = *(const f16x4*)&ht[l15][ks * 16 + 4 * hi];
        const f16x4 a1 = *(const f16x4*)&ht[16 + l15][ks * 16 + 4 * hi];
        acc[0][0] = __builtin_amdgcn_mfma_f32_16x16x16f16(a0, bhh[0][ks], acc[0][0], 0, 0, 0);
        acc[0][1] = __builtin_amdgcn_mfma_f32_16x16x16f16(a0, bhh[1][ks], acc[0][1], 0, 0, 0);
        acc[1][0] = __builtin_amdgcn_mfma_f32_16x16x16f16(a1, bhh[0][ks], acc[1][0], 0, 0, 0);
        acc[1][1] = __builtin_amdgcn_mfma_f32_16x16x16f16(a1, bhh[1][ks], acc[1][1], 0, 0, 0);
      }
      __syncthreads();   // all ht reads done before gl overwrites the union
#pragma unroll
      for (int mt = 0; mt < 2; ++mt)
#pragma unroll
        for (int nt = 0; nt < 2; ++nt) {
          const int col = (wv * 2 + nt) * 16 + l15;
#pragma unroll
          for (int r = 0; r < 4; ++r) gl[mt * 16 + 4 * hi + r][col] = acc[mt][nt][r];
        }
      __syncthreads();

      const int cur = t & 1;
#pragma unroll
      for (int half = 0; half < 2; ++half) {
        const int row = r0row + half * 16;
        const float gi = gl[row][j0],        gi1 = gl[row][j0 + 1];
        const float gf = gl[row][64 + j0],   gf1 = gl[row][64 + j0 + 1];
        const float gg = gl[row][128 + j0],  gg1 = gl[row][128 + j0 + 1];
        const float go = gl[row][192 + j0],  go1 = gl[row][192 + j0 + 1];
        float& ca = half ? c10 : c00;
        float& cb = half ? c11 : c01;
        ca = sigf(gf) * ca + sigf(gi) * tanh_fast(gg);
        cb = sigf(gf1) * cb + sigf(gi1) * tanh_fast(gg1);
        const f16 ha = (f16)(sigf(go) * tanh_fast(ca));
        const f16 hb = (f16)(sigf(go1) * tanh_fast(cb));
        unsigned hp = ((unsigned)__builtin_bit_cast(unsigned short, hb) << 16)
                    |  (unsigned)__builtin_bit_cast(unsigned short, ha);
        store_u32_l3(hbuf1 + ((size_t)cur * B_ + bg * 32 + row) * H_ + slC * 64 + j0, hp);
      }
      wait_vm0();
      __syncthreads();
      if (tid == 0) store_u32_l3(flags + (size_t)(192 + bg * 8 + slC) * 16, (unsigned)(t + 1));
    }
  }
}

// ---------------- MLP head ----------------
__global__ void head_g(const f16* __restrict__ h1, const float* __restrict__ w1,
                       const float* __restrict__ b1, const float* __restrict__ w2,
                       const float* __restrict__ b2, float* __restrict__ out) {
  __shared__ float ft[512];
  __shared__ float hm[256];
  const int b = blockIdx.x, tid = threadIdx.x;
  ft[tid * 2]     = (float)h1[(size_t)b * H_ + tid * 2];
  ft[tid * 2 + 1] = (float)h1[(size_t)b * H_ + tid * 2 + 1];
  __syncthreads();
  {
    float d = b1[tid];
    const float* wr = w1 + (size_t)tid * H_;
#pragma unroll 8
    for (int k = 0; k < H_; ++k) d += ft[k] * wr[k];
    hm[tid] = fmaxf(d, 0.f);
  }
  __syncthreads();
  if (tid < NC_) {
    float d = b2[tid];
    const float* wr = w2 + (size_t)tid * H2_;
#pragma unroll 8
    for (int k = 0; k < H2_; ++k) d += hm[k] * wr[k];
    out[(size_t)b * NC_ + tid] = d;
  }
}

// ---------------- launcher ----------------
extern "C" void kernel_launch(void* const* d_in, const int* in_sizes, int n_in,
                              void* d_out, int out_size, void* d_ws, size_t ws_size,
                              hipStream_t stream) {
  const float* x     = (const float*)d_in[0];
  const float* w_ih0 = (const float*)d_in[1];
  const float* w_hh0 = (const float*)d_in[2];
  const float* b_ih0 = (const float*)d_in[3];
  const float* b_hh0 = (const float*)d_in[4];
  const float* w_ih1 = (const float*)d_in[5];
  const float* w_hh1 = (const float*)d_in[6];
  const float* b_ih1 = (const float*)d_in[7];
  const float* b_hh1 = (const float*)d_in[8];
  const float* w1    = (const float*)d_in[9];
  const float* b1    = (const float*)d_in[10];
  const float* w2    = (const float*)d_in[11];
  const float* b2    = (const float*)d_in[12];
  float* out = (float*)d_out;

  char* p = (char*)d_ws;
  auto alloc = [&](size_t bytes) { char* r = p; p += (bytes + 255) & ~(size_t)255; return r; };
  f16*   h0seq  = (f16*)alloc((size_t)T_ * B_ * H_ * 2);        // 134 MB
  f16*   gxring = (f16*)alloc((size_t)16 * G4_ * B_ * 2);       // 16.8 MB, gate-major
  f16*   hbuf1  = (f16*)alloc((size_t)2 * B_ * H_ * 2);
  f16*   x16    = (f16*)alloc((size_t)B_ * T_ * IN_ * 2);
  f16*   wih0h  = (f16*)alloc((size_t)G4_ * IN_ * 2);
  f16*   whh0h  = (f16*)alloc((size_t)G4_ * H_ * 2);
  f16*   wih1h  = (f16*)alloc((size_t)G4_ * H_ * 2);
  f16*   whh1h  = (f16*)alloc((size_t)G4_ * H_ * 2);
  float* bias0c = (float*)alloc(G4_ * 4);
  float* bias1c = (float*)alloc(G4_ * 4);
  unsigned* flags = (unsigned*)alloc(256 * 64);

  hipMemsetAsync(flags, 0, 256 * 64, stream);
  cvt_f32_f16<<<2048, 256, 0, stream>>>(x, x16, B_ * T_ * IN_);
  cvt_f32_f16<<<512, 256, 0, stream>>>(w_ih0, wih0h, G4_ * IN_);
  cvt_f32_f16<<<2048, 256, 0, stream>>>(w_hh0, whh0h, G4_ * H_);
  cvt_f32_f16<<<2048, 256, 0, stream>>>(w_ih1, wih1h, G4_ * H_);
  cvt_f32_f16<<<2048, 256, 0, stream>>>(w_hh1, whh1h, G4_ * H_);
  bias_comb<<<8, 256, 0, stream>>>(b_ih0, b_hh0, bias0c, G4_);
  bias_comb<<<8, 256, 0, stream>>>(b_ih1, b_hh1, bias1c, G4_);

  fused_g<<<256, 512, 0, stream>>>(x16, wih0h, whh0h, wih1h, whh1h,
                                   bias0c, bias1c, h0seq, gxring, hbuf1, flags);
  head_g<<<B_, 256, 0, stream>>>(hbuf1 + (size_t)B_ * H_, w1, b1, w2, b2, out);
}